// Round 7
// baseline (71.858 us; speedup 1.0000x reference)
//
#include <hip/hip_runtime.h>
#include <math.h>

#define B_TOT 2048
#define IN_TOT 512
#define OUT_TOT 512
#define CPB 4             // cols per block
#define RPB 128           // rows per block (64 ty-slots x M=2)
#define M 2               // rows per thread
#define NQ 128            // k-quads

__global__ __launch_bounds__(256, 8) void morph_kernel(
    const float* __restrict__ x,
    const float* __restrict__ wdil,
    const float* __restrict__ wero,
    float* __restrict__ out)
{
    // [arr][col*512 + phys_quad*4 + e] : 2 * 4 cols * 512 k * 4B = 16 KB
    // staged ONCE; no barriers in the main loop. 8 blocks/CU -> 32 waves/CU.
    __shared__ float w_s[2][CPB * IN_TOT];

    const int tid = (int)threadIdx.x;
    const int tx  = tid & 3;      // col within block
    const int ty  = tid >> 2;     // row slot (0..63): rows ty, ty+64

    const int col0 = (int)blockIdx.x * CPB;
    const int row0 = (int)blockIdx.y * RPB;

    // ---- stage weights, source-side quad-XOR swizzle (involution, low 2 bits) ----
    // phys quad p of col c holds logical quad l = (p & ~3) | ((p ^ c) & 3)
#pragma unroll
    for (int i = 0; i < 2; ++i) {
        const int s  = i * 256 + tid;           // quad slot in [0, 512)
        const int c  = s >> 7;
        const int qp = s & 127;
        const int ql = (qp & ~3) | ((qp ^ c) & 3);
        const int g  = (col0 + c) * IN_TOT + ql * 4;
        *(float4*)&w_s[0][s * 4] = *(const float4*)(wdil + g);
        *(float4*)&w_s[1][s * 4] = *(const float4*)(wero + g);
    }
    __syncthreads();   // the only barrier

    float dil[M], ero[M];
#pragma unroll
    for (int mi = 0; mi < M; ++mi) { dil[mi] = -INFINITY; ero[mi] = INFINITY; }

    const float* xr0 = x + (size_t)(row0 + ty) * IN_TOT;
    const float* xr1 = xr0 + (size_t)64 * IN_TOT;

    const float* __restrict__ wdp = &w_s[0][tx * IN_TOT];
    const float* __restrict__ wep = &w_s[1][tx * IN_TOT];

#pragma unroll 4
    for (int q = 0; q < NQ; ++q) {
        const int ph = (q & ~3) | ((q ^ tx) & 3);   // 4 addrs x 16-lane bcast, conflict-free
        float4 wd4 = *(const float4*)(wdp + ph * 4);
        float4 we4 = *(const float4*)(wep + ph * 4);

        float4 xv0 = *(const float4*)(xr0 + q * 4);
        float4 xv1 = *(const float4*)(xr1 + q * 4);

        dil[0] = fmaxf(fmaxf(xv0.x + wd4.x, xv0.y + wd4.y), dil[0]);
        dil[0] = fmaxf(fmaxf(xv0.z + wd4.z, xv0.w + wd4.w), dil[0]);
        ero[0] = fminf(fminf(xv0.x - we4.x, xv0.y - we4.y), ero[0]);
        ero[0] = fminf(fminf(xv0.z - we4.z, xv0.w - we4.w), ero[0]);

        dil[1] = fmaxf(fmaxf(xv1.x + wd4.x, xv1.y + wd4.y), dil[1]);
        dil[1] = fmaxf(fmaxf(xv1.z + wd4.z, xv1.w + wd4.w), dil[1]);
        ero[1] = fminf(fminf(xv1.x - we4.x, xv1.y - we4.y), ero[1]);
        ero[1] = fminf(fminf(xv1.z - we4.z, xv1.w - we4.w), ero[1]);
    }

    float* op = out + (size_t)(row0 + ty) * OUT_TOT + col0 + tx;
    op[0] = dil[0] + ero[0];
    op[(size_t)64 * OUT_TOT] = dil[1] + ero[1];
}

extern "C" void kernel_launch(void* const* d_in, const int* in_sizes, int n_in,
                              void* d_out, int out_size, void* d_ws, size_t ws_size,
                              hipStream_t stream)
{
    const float* x  = (const float*)d_in[0];
    const float* wd = (const float*)d_in[1];
    const float* we = (const float*)d_in[2];
    float* out = (float*)d_out;

    dim3 grid(OUT_TOT / CPB, B_TOT / RPB);   // (128, 16) = 2048 blocks = 8/CU
    dim3 block(256);
    hipLaunchKernelGGL(morph_kernel, grid, block, 0, stream, x, wd, we, out);
}